// Round 5
// baseline (109.388 us; speedup 1.0000x reference)
//
#include <hip/hip_runtime.h>
#include <math.h>

// Problem constants (fixed by setup_inputs)
//   h: (32, 512, 320) f32, a_link/b_link: (256, 64) f32, rollout: 1 (unused)
// Outputs: A_out (32,512,512) f32  then probs (32,) f32, concatenated.
#define BATCH   32
#define NPTS    512
#define FDIM    320
#define FOBS    256
#define DK      64
#define MROWS   (BATCH * NPTS)            // 16384
#define A_ELEMS ((size_t)BATCH * NPTS * NPTS)  // 8388608

typedef __bf16  bf16x8 __attribute__((ext_vector_type(8)));
typedef float   f32x4  __attribute__((ext_vector_type(4)));
typedef ushort  u16x8  __attribute__((ext_vector_type(8)));
typedef ushort  u16x4  __attribute__((ext_vector_type(4)));

__device__ __forceinline__ ushort f2bf(float f) {   // RNE f32 -> bf16
    unsigned u = __builtin_bit_cast(unsigned, f);
    return (ushort)((u + 0x7fffu + ((u >> 16) & 1u)) >> 16);
}

__device__ __forceinline__ bf16x8 ld_bf8(const ushort* p) {
    return __builtin_bit_cast(bf16x8, *reinterpret_cast<const uint4*>(p));
}

// ---------------------------------------------------------------------------
// K0: Wt[n][k] = bf16( n<64 ? a_link[k][n] : b_link[k][n-64] )   (128 x 256)
//     Also zeroes the per-batch completion counters used by k2's fused probs
//     reduction (re-zeroed every call -> deterministic across replays).
// ---------------------------------------------------------------------------
__global__ __launch_bounds__(256) void k0_wt(const float* __restrict__ al,
                                             const float* __restrict__ bl,
                                             ushort* __restrict__ wt,
                                             unsigned* __restrict__ cnt) {
    const int n = blockIdx.x;            // 0..127
    const int k = threadIdx.x;           // 0..255
    if (n == 0 && k < BATCH) cnt[k] = 0u;
    const float* src = (n < 64) ? al : bl;
    const int nn = n & 63;
    wt[(size_t)n * FOBS + k] = f2bf(src[(size_t)k * DK + nn]);
}

// ---------------------------------------------------------------------------
// K1 (MFMA, no LDS, swapped operands): [hi|hj] = h[:,:256] @ W.
//   A-operand = Wt rows (streamed from L2), B-operand = h rows (cvt to bf16).
//   D[n][m]: lane l holds n = (l>>4)*4+r (4 consecutive!), m = l&15.
//   -> u16x4 (8 B) packed stores, 4 per lane.
// ---------------------------------------------------------------------------
__global__ __launch_bounds__(256) void k1_mfma(const float* __restrict__ h,
                                               const ushort* __restrict__ wt,
                                               ushort* __restrict__ hi,
                                               ushort* __restrict__ hj) {
    const int t  = threadIdx.x;
    const int w  = t >> 6;
    const int l  = t & 63;
    const int lr = l & 15;
    const int lg = l >> 4;
    const int rb = blockIdx.x * 32 + 16 * (w & 1);
    const int cb = 64 * (w >> 1);        // 0 -> hi, 64 -> hj

    // B-frags: h rows, f32 loads converted in-register (kept in VGPRs)
    const float* hrow = h + (size_t)(rb + lr) * FDIM;
    bf16x8 bfr[8];
#pragma unroll
    for (int ks = 0; ks < 8; ++ks) {
        const float* p = hrow + ks * 32 + lg * 8;
        float4 v0 = *reinterpret_cast<const float4*>(p);
        float4 v1 = *reinterpret_cast<const float4*>(p + 4);
        u16x8 u;
        u[0] = f2bf(v0.x); u[1] = f2bf(v0.y); u[2] = f2bf(v0.z); u[3] = f2bf(v0.w);
        u[4] = f2bf(v1.x); u[5] = f2bf(v1.y); u[6] = f2bf(v1.z); u[7] = f2bf(v1.w);
        bfr[ks] = __builtin_bit_cast(bf16x8, u);
    }

    f32x4 acc[4];
#pragma unroll
    for (int cf = 0; cf < 4; ++cf) acc[cf] = (f32x4){0.f, 0.f, 0.f, 0.f};

#pragma unroll
    for (int ks = 0; ks < 8; ++ks) {
#pragma unroll
        for (int cf = 0; cf < 4; ++cf) {
            bf16x8 afr = ld_bf8(&wt[(size_t)(cb + 16 * cf + lr) * FOBS + ks * 32 + lg * 8]);
            acc[cf] = __builtin_amdgcn_mfma_f32_16x16x32_bf16(afr, bfr[ks], acc[cf], 0, 0, 0);
        }
    }

    // epilogue: lane owns row m = rb+lr, cols (16cf + lg*4 .. +3) -> u16x4
    ushort* dst = (cb == 0) ? hi : hj;
    const size_t m = (size_t)(rb + lr);
#pragma unroll
    for (int cf = 0; cf < 4; ++cf) {
        u16x4 v;
#pragma unroll
        for (int r = 0; r < 4; ++r) v[r] = f2bf(acc[cf][r]);
        *reinterpret_cast<u16x4*>(&dst[m * DK + 16 * cf + lg * 4]) = v;
    }
}

// ---------------------------------------------------------------------------
// K2 (MFMA, swapped operands): per (b, 64x64 tile): logits = hi @ hj^T / 8.
//   A-operand = hj rows (wave w owns j-strip), B-operand = hi rows (4 itt).
//   D[j][i]: lane l holds j = (l>>4)*4+r (consecutive), i = l&15
//   -> epilogue writes float4 rows of A_out (nontemporal).
//   1D grid XCD-swizzled (id&7 = XCD, 4 whole batches per XCD -> L2-resident).
//   Fused probs: threadfence reduction, last block per batch sums 64 partials
//   in fixed order (deterministic).
// ---------------------------------------------------------------------------
__global__ __launch_bounds__(256, 4) void k2_mfma(const ushort* __restrict__ hi,
                                                  const ushort* __restrict__ hj,
                                                  float* __restrict__ Aout,
                                                  float* __restrict__ partials,
                                                  unsigned* __restrict__ cnt,
                                                  float* __restrict__ probs) {
    __shared__ float red[4];
    __shared__ int   is_last;
    const int id  = blockIdx.x;
    const int sub = id >> 3;
    const int b   = (id & 7) * 4 + (sub >> 6);
    const int it  = (sub >> 3) & 7;
    const int jt  = sub & 7;

    const int t  = threadIdx.x;
    const int w  = t >> 6;
    const int l  = t & 63;
    const int lr = l & 15;
    const int lg = l >> 4;
    const int i0 = it * 64, j0 = jt * 64;

    const ushort* hib = hi + ((size_t)b * NPTS + i0) * DK;
    const ushort* hjb = hj + ((size_t)b * NPTS + j0) * DK;

    // A-frags: hj rows for this wave's j-strip
    bf16x8 afr[2];
#pragma unroll
    for (int ks = 0; ks < 2; ++ks)
        afr[ks] = ld_bf8(&hjb[(size_t)(16 * w + lr) * DK + ks * 32 + lg * 8]);

    // B-frags: hi rows for all 4 i-subtiles
    bf16x8 bfr[4][2];
#pragma unroll
    for (int itt = 0; itt < 4; ++itt)
#pragma unroll
        for (int ks = 0; ks < 2; ++ks)
            bfr[itt][ks] = ld_bf8(&hib[(size_t)(16 * itt + lr) * DK + ks * 32 + lg * 8]);

    f32x4 acc[4];
#pragma unroll
    for (int itt = 0; itt < 4; ++itt) acc[itt] = (f32x4){0.f, 0.f, 0.f, 0.f};

#pragma unroll
    for (int ks = 0; ks < 2; ++ks)
#pragma unroll
        for (int itt = 0; itt < 4; ++itt)
            acc[itt] = __builtin_amdgcn_mfma_f32_16x16x32_bf16(
                afr[ks], bfr[itt][ks], acc[itt], 0, 0, 0);

    // fused epilogue: lane owns A_out[row][colbase..colbase+3]
    float lsum = 0.f;
    const int colbase = j0 + 16 * w + lg * 4;
#pragma unroll
    for (int itt = 0; itt < 4; ++itt) {
        const int row = i0 + 16 * itt + lr;
        f32x4 ov;
#pragma unroll
        for (int r = 0; r < 4; ++r) {
            float x  = acc[itt][r] * 0.125f;   // / sqrt(64), tau = 1
            float ax = fabsf(x);
            float nl = __logf(1.0f + __expf(-ax));   // -log(sel), sel >= 0.5
            bool diag = (row == colbase + r);
            ov[r] = (diag || x > 0.f) ? 1.f : 0.f;
            if (!diag) lsum -= nl;
        }
        __builtin_nontemporal_store(ov,
            reinterpret_cast<f32x4*>(&Aout[((size_t)b * NPTS + row) * NPTS + colbase]));
    }

    // deterministic block reduction of lsum
#pragma unroll
    for (int off = 32; off > 0; off >>= 1) lsum += __shfl_down(lsum, off);
    if (l == 0) red[w] = lsum;
    __syncthreads();
    if (t == 0) {
        float s = (red[0] + red[1]) + (red[2] + red[3]);
        partials[(size_t)b * 64 + it * 8 + jt] = s;
        __threadfence();                               // release partial
        unsigned old = atomicAdd(&cnt[b], 1u);         // device scope
        is_last = (old == 63u) ? 1 : 0;
    }
    __syncthreads();

    if (is_last && t < 64) {
        __threadfence();                               // acquire
        const volatile float* pp = partials + (size_t)b * 64;
        float s = pp[t];
#pragma unroll
        for (int off = 32; off > 0; off >>= 1) s += __shfl_down(s, off);
        if (t == 0) probs[b] = s;
    }
}

extern "C" void kernel_launch(void* const* d_in, const int* in_sizes, int n_in,
                              void* d_out, int out_size, void* d_ws, size_t ws_size,
                              hipStream_t stream) {
    const float* h  = (const float*)d_in[0];
    const float* al = (const float*)d_in[1];
    const float* bl = (const float*)d_in[2];
    float* out = (float*)d_out;

    ushort* hi      = (ushort*)d_ws;                      // 16384*64 bf16 (2 MB)
    ushort* hj      = hi + (size_t)MROWS * DK;            // 16384*64 bf16 (2 MB)
    ushort* wt      = hj + (size_t)MROWS * DK;            // 128*256 bf16 (64 KB)
    float* partials = (float*)(wt + 128 * FOBS);          // 32*64 f32 (8 KB)
    unsigned* cnt   = (unsigned*)(partials + BATCH * 64); // 32 u32

    k0_wt<<<128, 256, 0, stream>>>(al, bl, wt, cnt);

    k1_mfma<<<MROWS / 32, 256, 0, stream>>>(h, wt, hi, hj);

    k2_mfma<<<(NPTS / 64) * (NPTS / 64) * BATCH, 256, 0, stream>>>(
        hi, hj, out, partials, cnt, out + A_ELEMS);
}

// Round 6
// 38.703 us; speedup vs baseline: 2.8264x; 2.8264x over previous
//
#include <hip/hip_runtime.h>
#include <math.h>

// Problem constants (fixed by setup_inputs)
//   h: (32, 512, 320) f32, a_link/b_link: (256, 64) f32, rollout: 1 (unused)
// Outputs: A_out (32,512,512) f32  then probs (32,) f32, concatenated.
#define BATCH   32
#define NPTS    512
#define FDIM    320
#define FOBS    256
#define DK      64
#define MROWS   (BATCH * NPTS)            // 16384
#define A_ELEMS ((size_t)BATCH * NPTS * NPTS)  // 8388608

typedef __bf16  bf16x8 __attribute__((ext_vector_type(8)));
typedef float   f32x4  __attribute__((ext_vector_type(4)));
typedef ushort  u16x8  __attribute__((ext_vector_type(8)));
typedef ushort  u16x4  __attribute__((ext_vector_type(4)));

__device__ __forceinline__ ushort f2bf(float f) {   // RNE f32 -> bf16
    unsigned u = __builtin_bit_cast(unsigned, f);
    return (ushort)((u + 0x7fffu + ((u >> 16) & 1u)) >> 16);
}

__device__ __forceinline__ bf16x8 ld_bf8(const ushort* p) {
    return __builtin_bit_cast(bf16x8, *reinterpret_cast<const uint4*>(p));
}

// ---------------------------------------------------------------------------
// K0: Wt[n][k] = bf16( n<64 ? a_link[k][n] : b_link[k][n-64] )   (128 x 256)
// ---------------------------------------------------------------------------
__global__ __launch_bounds__(256) void k0_wt(const float* __restrict__ al,
                                             const float* __restrict__ bl,
                                             ushort* __restrict__ wt) {
    const int n = blockIdx.x;            // 0..127
    const int k = threadIdx.x;           // 0..255
    const float* src = (n < 64) ? al : bl;
    const int nn = n & 63;
    wt[(size_t)n * FOBS + k] = f2bf(src[(size_t)k * DK + nn]);
}

// ---------------------------------------------------------------------------
// K1 (MFMA, no LDS, swapped operands): [hi|hj] = h[:,:256] @ W.
//   A-operand = Wt rows (streamed from L2), B-operand = h rows (cvt to bf16).
//   D[n][m]: lane l holds n = (l>>4)*4+r (4 consecutive), m = l&15.
//   -> u16x4 (8 B) packed stores, 4 per lane.
// ---------------------------------------------------------------------------
__global__ __launch_bounds__(256) void k1_mfma(const float* __restrict__ h,
                                               const ushort* __restrict__ wt,
                                               ushort* __restrict__ hi,
                                               ushort* __restrict__ hj) {
    const int t  = threadIdx.x;
    const int w  = t >> 6;
    const int l  = t & 63;
    const int lr = l & 15;
    const int lg = l >> 4;
    const int rb = blockIdx.x * 32 + 16 * (w & 1);
    const int cb = 64 * (w >> 1);        // 0 -> hi, 64 -> hj

    // B-frags: h rows, f32 loads converted in-register (kept in VGPRs)
    const float* hrow = h + (size_t)(rb + lr) * FDIM;
    bf16x8 bfr[8];
#pragma unroll
    for (int ks = 0; ks < 8; ++ks) {
        const float* p = hrow + ks * 32 + lg * 8;
        float4 v0 = *reinterpret_cast<const float4*>(p);
        float4 v1 = *reinterpret_cast<const float4*>(p + 4);
        u16x8 u;
        u[0] = f2bf(v0.x); u[1] = f2bf(v0.y); u[2] = f2bf(v0.z); u[3] = f2bf(v0.w);
        u[4] = f2bf(v1.x); u[5] = f2bf(v1.y); u[6] = f2bf(v1.z); u[7] = f2bf(v1.w);
        bfr[ks] = __builtin_bit_cast(bf16x8, u);
    }

    f32x4 acc[4];
#pragma unroll
    for (int cf = 0; cf < 4; ++cf) acc[cf] = (f32x4){0.f, 0.f, 0.f, 0.f};

#pragma unroll
    for (int ks = 0; ks < 8; ++ks) {
#pragma unroll
        for (int cf = 0; cf < 4; ++cf) {
            bf16x8 afr = ld_bf8(&wt[(size_t)(cb + 16 * cf + lr) * FOBS + ks * 32 + lg * 8]);
            acc[cf] = __builtin_amdgcn_mfma_f32_16x16x32_bf16(afr, bfr[ks], acc[cf], 0, 0, 0);
        }
    }

    // epilogue: lane owns row m = rb+lr, cols (16cf + lg*4 .. +3) -> u16x4
    ushort* dst = (cb == 0) ? hi : hj;
    const size_t m = (size_t)(rb + lr);
#pragma unroll
    for (int cf = 0; cf < 4; ++cf) {
        u16x4 v;
#pragma unroll
        for (int r = 0; r < 4; ++r) v[r] = f2bf(acc[cf][r]);
        *reinterpret_cast<u16x4*>(&dst[m * DK + 16 * cf + lg * 4]) = v;
    }
}

// ---------------------------------------------------------------------------
// K2 (MFMA, swapped operands): per (b, 64x64 tile): logits = hi @ hj^T / 8.
//   A-operand = hj rows (wave w owns j-strip), B-operand = hi rows (4 itt).
//   D[j][i]: lane l holds j = (l>>4)*4+r (consecutive), i = l&15
//   -> epilogue writes float4 runs of A_out rows (nontemporal).
//   1D grid XCD-swizzled (id&7 = XCD, 4 whole batches per XCD -> L2-resident).
//   NO device-scope fences/atomics here (round-5 lesson: __threadfence per
//   block = L2 writeback storm on non-coherent XCD L2s, +60 us).
// ---------------------------------------------------------------------------
__global__ __launch_bounds__(256, 4) void k2_mfma(const ushort* __restrict__ hi,
                                                  const ushort* __restrict__ hj,
                                                  float* __restrict__ Aout,
                                                  float* __restrict__ partials) {
    __shared__ float red[4];
    const int id  = blockIdx.x;
    const int sub = id >> 3;
    const int b   = (id & 7) * 4 + (sub >> 6);
    const int it  = (sub >> 3) & 7;
    const int jt  = sub & 7;

    const int t  = threadIdx.x;
    const int w  = t >> 6;
    const int l  = t & 63;
    const int lr = l & 15;
    const int lg = l >> 4;
    const int i0 = it * 64, j0 = jt * 64;

    const ushort* hib = hi + ((size_t)b * NPTS + i0) * DK;
    const ushort* hjb = hj + ((size_t)b * NPTS + j0) * DK;

    // A-frags: hj rows for this wave's j-strip
    bf16x8 afr[2];
#pragma unroll
    for (int ks = 0; ks < 2; ++ks)
        afr[ks] = ld_bf8(&hjb[(size_t)(16 * w + lr) * DK + ks * 32 + lg * 8]);

    // B-frags: hi rows for all 4 i-subtiles
    bf16x8 bfr[4][2];
#pragma unroll
    for (int itt = 0; itt < 4; ++itt)
#pragma unroll
        for (int ks = 0; ks < 2; ++ks)
            bfr[itt][ks] = ld_bf8(&hib[(size_t)(16 * itt + lr) * DK + ks * 32 + lg * 8]);

    f32x4 acc[4];
#pragma unroll
    for (int itt = 0; itt < 4; ++itt) acc[itt] = (f32x4){0.f, 0.f, 0.f, 0.f};

#pragma unroll
    for (int ks = 0; ks < 2; ++ks)
#pragma unroll
        for (int itt = 0; itt < 4; ++itt)
            acc[itt] = __builtin_amdgcn_mfma_f32_16x16x32_bf16(
                afr[ks], bfr[itt][ks], acc[itt], 0, 0, 0);

    // fused epilogue: lane owns A_out[row][colbase..colbase+3]
    float lsum = 0.f;
    const int colbase = j0 + 16 * w + lg * 4;
#pragma unroll
    for (int itt = 0; itt < 4; ++itt) {
        const int row = i0 + 16 * itt + lr;
        f32x4 ov;
#pragma unroll
        for (int r = 0; r < 4; ++r) {
            float x  = acc[itt][r] * 0.125f;   // / sqrt(64), tau = 1
            float ax = fabsf(x);
            float nl = __logf(1.0f + __expf(-ax));   // -log(sel), sel >= 0.5
            bool diag = (row == colbase + r);
            ov[r] = (diag || x > 0.f) ? 1.f : 0.f;
            if (!diag) lsum -= nl;
        }
        __builtin_nontemporal_store(ov,
            reinterpret_cast<f32x4*>(&Aout[((size_t)b * NPTS + row) * NPTS + colbase]));
    }

    // deterministic block reduction of lsum
#pragma unroll
    for (int off = 32; off > 0; off >>= 1) lsum += __shfl_down(lsum, off);
    if (l == 0) red[w] = lsum;
    __syncthreads();
    if (t == 0) {
        float s = (red[0] + red[1]) + (red[2] + red[3]);
        partials[(size_t)b * 64 + it * 8 + jt] = s;
    }
}

// ---------------------------------------------------------------------------
// K3: probs[b] = sum of 64 tile partials (deterministic wave reduction)
// ---------------------------------------------------------------------------
__global__ __launch_bounds__(64) void k3_reduce(const float* __restrict__ partials,
                                                float* __restrict__ probs) {
    int b = blockIdx.x;
    float s = partials[(size_t)b * 64 + threadIdx.x];
#pragma unroll
    for (int off = 32; off > 0; off >>= 1) s += __shfl_down(s, off);
    if (threadIdx.x == 0) probs[b] = s;
}

extern "C" void kernel_launch(void* const* d_in, const int* in_sizes, int n_in,
                              void* d_out, int out_size, void* d_ws, size_t ws_size,
                              hipStream_t stream) {
    const float* h  = (const float*)d_in[0];
    const float* al = (const float*)d_in[1];
    const float* bl = (const float*)d_in[2];
    float* out = (float*)d_out;

    ushort* hi      = (ushort*)d_ws;                      // 16384*64 bf16 (2 MB)
    ushort* hj      = hi + (size_t)MROWS * DK;            // 16384*64 bf16 (2 MB)
    ushort* wt      = hj + (size_t)MROWS * DK;            // 128*256 bf16 (64 KB)
    float* partials = (float*)(wt + 128 * FOBS);          // 32*64 f32 (8 KB)

    k0_wt<<<128, 256, 0, stream>>>(al, bl, wt);

    k1_mfma<<<MROWS / 32, 256, 0, stream>>>(h, wt, hi, hj);

    k2_mfma<<<(NPTS / 64) * (NPTS / 64) * BATCH, 256, 0, stream>>>(
        hi, hj, out, partials);

    k3_reduce<<<BATCH, 64, 0, stream>>>(partials, out + A_ELEMS);
}